// Round 1
// baseline (347.583 us; speedup 1.0000x reference)
//
#include <hip/hip_runtime.h>

#define LQN 2046
#define LL  2048
#define CC  512
#define DD  64

typedef float  f32x4 __attribute__((ext_vector_type(4)));
typedef float  f32x2 __attribute__((ext_vector_type(2)));
typedef __bf16 b16x8 __attribute__((ext_vector_type(8)));
typedef unsigned int u32x4 __attribute__((ext_vector_type(4)));

static __device__ __forceinline__ unsigned short f2bf(float f) {
  union { float f; unsigned u; } v; v.f = f;
  return (unsigned short)((v.u + 0x7fffu + ((v.u >> 16) & 1u)) >> 16);
}

static __device__ __forceinline__ f32x4 mfma16(b16x8 a, b16x8 b, f32x4 c) {
  return __builtin_amdgcn_mfma_f32_16x16x32_bf16(a, b, c, 0, 0, 0);
}

// ---------------- Kernel 1: grouped-conv QKV projections (MFMA) --------------
// out[b, oc, t] = sum_{ci,k} in[b, g*64+ci, t+k] * w[oc, ci, k], g = oc/64
// GEMM view per (b,g): [64 oc] x [K=192 (ktap*64+ci)] x [t]
// grid (16 t-tiles, 8 groups, 8 batch) x 256 threads
__global__ __launch_bounds__(256) void conv_qkv_kernel(
    const float* __restrict__ in, const float* __restrict__ qw,
    const float* __restrict__ kw, const float* __restrict__ vw,
    unsigned short* __restrict__ qo, unsigned short* __restrict__ ko,
    unsigned short* __restrict__ vo)
{
  __shared__ __align__(16) unsigned short inT[130 * 72];  // [t][ci] bf16, pad 72
  __shared__ __align__(16) unsigned short buf[128 * 72];  // transpose buffer

  const int tile = blockIdx.x, g = blockIdx.y, b = blockIdx.z;
  const int t0 = tile * 128;
  const int tid = threadIdx.x;
  const int lane = tid & 63;
  const int wv = tid >> 6;
  const int r0 = lane & 15, qh = lane >> 4;

  // ---- stage input tile transposed to [t][ci] bf16 ----
  {
    const int ci = tid & 63, ch = tid >> 6;
    const float* src = in + ((size_t)(b * CC + g * 64 + ci)) * LL;
    #pragma unroll
    for (int i = 0; i < 8; ++i) {
      int t = ch * 32 + i * 4;
      f32x4 d = *(const f32x4*)(src + t0 + t);
      inT[(t + 0) * 72 + ci] = f2bf(d.x);
      inT[(t + 1) * 72 + ci] = f2bf(d.y);
      inT[(t + 2) * 72 + ci] = f2bf(d.z);
      inT[(t + 3) * 72 + ci] = f2bf(d.w);
    }
    if (ch == 0) {
      #pragma unroll
      for (int e = 0; e < 2; ++e) {
        int t = 128 + e;
        int tg = t0 + t; if (tg > LL - 1) tg = LL - 1;
        inT[t * 72 + ci] = f2bf(src[tg]);
      }
    }
  }
  __syncthreads();

  const float* wptr[3] = {qw, kw, vw};
  const f32x4 zero4 = {0.f, 0.f, 0.f, 0.f};

  for (int p = 0; p < 3; ++p) {
    // ---- weight A-fragments: lane holds W[oc=wv*16+r0][k-chunk], k=ktap*64+ci
    b16x8 aW[6];
    {
      const float* wb = wptr[p] + (size_t)(g * 64 + wv * 16 + r0) * 192;
      #pragma unroll
      for (int kc = 0; kc < 6; ++kc) {
        const int ktap = kc >> 1;
        const int cib = (kc & 1) * 32 + qh * 8;
        union { b16x8 v; unsigned short u[8]; } fr;
        #pragma unroll
        for (int j = 0; j < 8; ++j)
          fr.u[j] = f2bf(wb[(cib + j) * 3 + ktap]);
        aW[kc] = fr.v;
      }
    }
    f32x4 acc[8];
    #pragma unroll
    for (int nt = 0; nt < 8; ++nt) acc[nt] = zero4;
    #pragma unroll
    for (int kc = 0; kc < 6; ++kc) {
      const int radd = kc >> 1;                 // tap offset in t
      const int colh = (kc & 1) * 32 + qh * 8;  // ci offset (halfwords)
      #pragma unroll
      for (int nt = 0; nt < 8; ++nt) {
        const int trow = nt * 16 + r0 + radd;
        b16x8 bI = *(const b16x8*)&inT[trow * 72 + colh];
        acc[nt] = mfma16(aW[kc], bI, acc[nt]);
      }
    }
    __syncthreads();   // previous proj's buf readers are done
    if (p < 2) {
      // Q/K: transpose to [t][oc] then coalesced t-major store [B,H,LQ,64]
      #pragma unroll
      for (int nt = 0; nt < 8; ++nt) {
        const int t = nt * 16 + r0;
        #pragma unroll
        for (int r = 0; r < 4; ++r)
          buf[t * 72 + wv * 16 + qh * 4 + r] = f2bf(acc[nt][r]);
      }
      __syncthreads();
      unsigned short* dst = (p == 0 ? qo : ko) +
          ((size_t)(b * 8 + g) * LQN + t0) * DD;
      #pragma unroll
      for (int it = 0; it < 4; ++it) {
        const int id = it * 256 + tid;
        const int t = id >> 3, c8 = id & 7;
        if (t0 + t < LQN)
          *(u32x4*)(dst + t * DD + c8 * 8) = *(const u32x4*)&buf[t * 72 + c8 * 8];
      }
    } else {
      // V: keep d-major, padded row length 2048
      #pragma unroll
      for (int nt = 0; nt < 8; ++nt) {
        const int t = nt * 16 + r0;
        #pragma unroll
        for (int r = 0; r < 4; ++r)
          buf[(wv * 16 + qh * 4 + r) * 136 + t] = f2bf(acc[nt][r]);
      }
      __syncthreads();
      unsigned short* dst = vo + ((size_t)(b * CC + g * 64)) * LL + t0;
      #pragma unroll
      for (int it = 0; it < 4; ++it) {
        const int id = it * 256 + tid;
        const int row = id >> 4, c16 = id & 15;
        *(u32x4*)(dst + (size_t)row * LL + c16 * 8) =
            *(const u32x4*)&buf[row * 136 + c16 * 8];
      }
    }
    __syncthreads();
  }
}

// ---------------- Kernel 2: causal flash attention + residual ----------------
// block = (b,h, 64-row Q tile); 4 waves, wave owns 16 q-rows.
// K tile [64 kv][64 d], Vt tile [64 d][64 kv], both XOR-swizzled in LDS.
__global__ __launch_bounds__(256) void attn_kernel(
    const unsigned short* __restrict__ qg, const unsigned short* __restrict__ kg,
    const unsigned short* __restrict__ vg, const float* __restrict__ initw,
    float* __restrict__ out)
{
  __shared__ __align__(16) unsigned char smem[24960];
  unsigned short* Kl = (unsigned short*)smem;            // 8 KB
  unsigned short* Vl = (unsigned short*)(smem + 8192);   // 8 KB
  const int qt = 31 - (int)blockIdx.x;   // big blocks dispatch first
  const int bh = blockIdx.y;
  const int b = bh >> 3, h = bh & 7;
  const int tid = threadIdx.x, lane = tid & 63, wv = tid >> 6;
  const int r0 = lane & 15, qh = lane >> 4;
  unsigned short* Pl = (unsigned short*)(smem + 16768) + wv * 1024; // 2KB/wave

  const size_t kqbase = (size_t)bh * LQN * DD;
  const size_t vbase  = ((size_t)(b * CC + h * 64)) * LL;

  int qrow = qt * 64 + wv * 16 + r0; if (qrow > LQN - 1) qrow = LQN - 1;
  const unsigned short* qp = qg + kqbase + (size_t)qrow * DD;
  const b16x8 aQ0 = *(const b16x8*)(qp + qh * 8);
  const b16x8 aQ1 = *(const b16x8*)(qp + 32 + qh * 8);

  const f32x4 zero4 = {0.f, 0.f, 0.f, 0.f};
  f32x4 o[4];
  #pragma unroll
  for (int dt = 0; dt < 4; ++dt) o[dt] = zero4;
  float mrow[4] = {-1e30f, -1e30f, -1e30f, -1e30f};
  float lrow[4] = {0.f, 0.f, 0.f, 0.f};
  const float SCL = 0.51006979f;  // log2(e)/sqrt(8)

  for (int kt = 0; kt <= qt; ++kt) {
    const int kv0 = kt * 64;
    __syncthreads();   // previous tile fully consumed
    #pragma unroll
    for (int it = 0; it < 2; ++it) {            // K tile
      const int id = it * 256 + tid;
      const int r = id >> 3, c = id & 7;
      int sr = kv0 + r; if (sr > LQN - 1) sr = LQN - 1;
      *(u32x4*)(Kl + r * 64 + ((c ^ (r & 7)) * 8)) =
          *(const u32x4*)(kg + kqbase + (size_t)sr * DD + c * 8);
    }
    #pragma unroll
    for (int it = 0; it < 2; ++it) {            // Vt tile (d-major rows)
      const int id = it * 256 + tid;
      const int r = id >> 3, c = id & 7;
      *(u32x4*)(Vl + r * 64 + ((c ^ (r & 7)) * 8)) =
          *(const u32x4*)(vg + vbase + (size_t)r * LL + kv0 + c * 8);
    }
    __syncthreads();

    const bool diag = (kt == qt);
    const int ntmax = diag ? wv : 3;
    f32x4 s[4];
    #pragma unroll
    for (int nt = 0; nt < 4; ++nt) s[nt] = zero4;
    for (int nt = 0; nt <= ntmax; ++nt) {       // S = Q K^T
      const int krow = nt * 16 + r0;
      const unsigned short* kr = Kl + krow * 64;
      const int sw = krow & 7;
      b16x8 b0 = *(const b16x8*)(kr + ((qh ^ sw) * 8));
      b16x8 b1 = *(const b16x8*)(kr + (((4 + qh) ^ sw) * 8));
      s[nt] = mfma16(aQ0, b0, s[nt]);
      s[nt] = mfma16(aQ1, b1, s[nt]);
    }
    #pragma unroll
    for (int nt = 0; nt < 4; ++nt) s[nt] *= SCL;
    if (diag) {
      #pragma unroll
      for (int nt = 0; nt < 4; ++nt) {
        if (nt > ntmax) {
          s[nt] = (f32x4){-1e30f, -1e30f, -1e30f, -1e30f};
        } else {
          #pragma unroll
          for (int r = 0; r < 4; ++r) {
            const int rowg = qt * 64 + wv * 16 + qh * 4 + r;
            const int colg = kv0 + nt * 16 + r0;
            if (colg > rowg) s[nt][r] = -1e30f;
          }
        }
      }
    }
    // ---- online softmax (exp2 domain), wave-parallel row reductions ----
    f32x4 corrv;
    #pragma unroll
    for (int r = 0; r < 4; ++r) {
      float s0 = s[0][r], s1 = s[1][r], s2 = s[2][r], s3 = s[3][r];
      float mt = fmaxf(fmaxf(s0, s1), fmaxf(s2, s3));
      #pragma unroll
      for (int mm = 1; mm <= 8; mm <<= 1) mt = fmaxf(mt, __shfl_xor(mt, mm));
      const float mn = fmaxf(mrow[r], mt);
      const float corr = __builtin_amdgcn_exp2f(mrow[r] - mn);
      mrow[r] = mn;
      const float p0 = __builtin_amdgcn_exp2f(s0 - mn);
      const float p1 = __builtin_amdgcn_exp2f(s1 - mn);
      const float p2 = __builtin_amdgcn_exp2f(s2 - mn);
      const float p3 = __builtin_amdgcn_exp2f(s3 - mn);
      float ps = p0 + p1 + p2 + p3;
      #pragma unroll
      for (int mm = 1; mm <= 8; mm <<= 1) ps += __shfl_xor(ps, mm);
      lrow[r] = lrow[r] * corr + ps;
      corrv[r] = corr;
      // write P row (wave-private, swizzled)
      const int rl = qh * 4 + r;
      const int sw = rl & 7;
      unsigned short* pw = Pl + rl * 64;
      pw[(((r0) >> 3) ^ sw) * 8 + (r0 & 7)]        = f2bf(p0);
      pw[(((16 + r0) >> 3) ^ sw) * 8 + (r0 & 7)]   = f2bf(p1);
      pw[(((32 + r0) >> 3) ^ sw) * 8 + (r0 & 7)]   = f2bf(p2);
      pw[(((48 + r0) >> 3) ^ sw) * 8 + (r0 & 7)]   = f2bf(p3);
    }
    #pragma unroll
    for (int dt = 0; dt < 4; ++dt) o[dt] *= corrv;
    // ---- O += P V ----
    #pragma unroll
    for (int kc = 0; kc < 2; ++kc) {
      b16x8 aP = *(const b16x8*)(Pl + r0 * 64 + (((kc * 4 + qh) ^ (r0 & 7)) * 8));
      #pragma unroll
      for (int dt = 0; dt < 4; ++dt) {
        const int vrow = dt * 16 + r0;
        b16x8 bv = *(const b16x8*)(Vl + vrow * 64 + (((kc * 4 + qh) ^ (vrow & 7)) * 8));
        o[dt] = mfma16(aP, bv, o[dt]);
      }
    }
  }

  // ---- epilogue: + init_weight^T, write pre-LN feat ----
  __syncthreads();
  float* initL = (float*)smem;   // [64 c][65] tile, coalesced stage
  {
    const int cc = tid >> 2, qgrp = (tid & 3) * 16;
    const float* src = initw + (size_t)(b * CC + h * 64 + cc) * LQN;
    #pragma unroll
    for (int u = 0; u < 8; ++u) {
      int col = qt * 64 + qgrp + u * 2;
      if (col > LQN - 2) col = LQN - 2;
      f32x2 d = *(const f32x2*)(src + col);
      initL[cc * 65 + qgrp + u * 2]     = d.x;
      initL[cc * 65 + qgrp + u * 2 + 1] = d.y;
    }
  }
  __syncthreads();
  #pragma unroll
  for (int r = 0; r < 4; ++r) {
    const int ql = wv * 16 + qh * 4 + r;
    const int qgl = qt * 64 + ql;
    if (qgl >= LQN) continue;
    const float invl = 1.0f / lrow[r];
    float* dst = out + ((size_t)(b * LQN + qgl)) * CC + h * 64;
    #pragma unroll
    for (int dt = 0; dt < 4; ++dt)
      dst[dt * 16 + r0] = o[dt][r] * invl + initL[(dt * 16 + r0) * 65 + ql];
  }
}

// ---------------- Kernel 3: LayerNorm over C, in-place on d_out --------------
__global__ __launch_bounds__(256) void ln_kernel(
    const float* __restrict__ gamma, const float* __restrict__ beta,
    float* __restrict__ out)
{
  const int row = blockIdx.x * 4 + ((int)threadIdx.x >> 6);
  const int lane = threadIdx.x & 63;
  if (row >= 8 * LQN) return;
  float* p = out + (size_t)row * CC;
  f32x4 x0 = *(const f32x4*)(p + lane * 8);
  f32x4 x1 = *(const f32x4*)(p + lane * 8 + 4);
  float s  = x0.x + x0.y + x0.z + x0.w + x1.x + x1.y + x1.z + x1.w;
  float sq = x0.x*x0.x + x0.y*x0.y + x0.z*x0.z + x0.w*x0.w
           + x1.x*x1.x + x1.y*x1.y + x1.z*x1.z + x1.w*x1.w;
  #pragma unroll
  for (int mm = 1; mm <= 32; mm <<= 1) {
    s  += __shfl_xor(s, mm);
    sq += __shfl_xor(sq, mm);
  }
  const float mu = s * (1.f / 512.f);
  const float var = sq * (1.f / 512.f) - mu * mu;
  const float rstd = rsqrtf(var + 1e-5f);
  f32x4 g0 = *(const f32x4*)(gamma + lane * 8);
  f32x4 g1 = *(const f32x4*)(gamma + lane * 8 + 4);
  f32x4 b0 = *(const f32x4*)(beta + lane * 8);
  f32x4 b1 = *(const f32x4*)(beta + lane * 8 + 4);
  x0 = (x0 - mu) * rstd * g0 + b0;
  x1 = (x1 - mu) * rstd * g1 + b1;
  *(f32x4*)(p + lane * 8)     = x0;
  *(f32x4*)(p + lane * 8 + 4) = x1;
}

extern "C" void kernel_launch(void* const* d_in, const int* in_sizes, int n_in,
                              void* d_out, int out_size, void* d_ws, size_t ws_size,
                              hipStream_t stream)
{
  const float* input = (const float*)d_in[0];
  const float* initw = (const float*)d_in[1];
  const float* qw    = (const float*)d_in[2];
  const float* kw    = (const float*)d_in[3];
  const float* vw    = (const float*)d_in[4];
  const float* gamma = (const float*)d_in[5];
  const float* beta  = (const float*)d_in[6];
  float* outp = (float*)d_out;

  // workspace: q (16MB), k (16MB), v (16MB padded [B,C,2048] bf16)
  unsigned short* q = (unsigned short*)d_ws;
  unsigned short* k = q + (16u * 1024u * 1024u / 2u);
  unsigned short* v = q + (32u * 1024u * 1024u / 2u);

  hipLaunchKernelGGL(conv_qkv_kernel, dim3(16, 8, 8), dim3(256), 0, stream,
                     input, qw, kw, vw, q, k, v);
  hipLaunchKernelGGL(attn_kernel, dim3(32, 64), dim3(256), 0, stream,
                     q, k, v, initw, outp);
  hipLaunchKernelGGL(ln_kernel, dim3(4092), dim3(256), 0, stream,
                     gamma, beta, outp);
}